// Round 9
// baseline (170.726 us; speedup 1.0000x reference)
//
#include <hip/hip_runtime.h>
#include <hip/hip_bf16.h>

// Problem constants (N=4096 rows, D=2048 cols, T=0.5 -> 1/T = 2)
#define NR 4096
#define DD 2048
#define INV_T 2.0f
// fp8 path (colsum): a_n*32 in e4m3 range; dot accumulates 1024*sim
#define QSCALE 32.0f
#define ACC_TO_LOGIT (INV_T / (QSCALE * QSCALE))  // 2/1024, colsum dot
// fp4 path (gemm): a_n*64 ~ N(0,1.41) into e2m1 range ±6 (±4.2 sigma);
// MFMA acc = 4096*sim
#define QS4 64.0f
#define ACC4_TO_LOGIT (INV_T / (QS4 * QS4))  // 2/4096, gemm logits

typedef __attribute__((ext_vector_type(2))) float floatx2;
typedef __attribute__((ext_vector_type(4))) float floatx4;
typedef __attribute__((ext_vector_type(4))) int int4v;
typedef __attribute__((ext_vector_type(8))) int int8v;

static __device__ __forceinline__ void async_copy16(const void* g, void* lds) {
  __builtin_amdgcn_global_load_lds((const __attribute__((address_space(1))) void*)g,
                                   (__attribute__((address_space(3))) void*)lds,
                                   16, 0, 0);
}

// e2m1 encode of pre-scaled x: values {0,.5,1,1.5,2,3,4,6}, clamp at 6,
// round-to-nearest via midpoint thresholds. Returns 4-bit code.
static __device__ __forceinline__ unsigned int enc4(float x) {
  float u = fminf(fabsf(x), 6.0f);
  int c = (u >= 0.25f) + (u >= 0.75f) + (u >= 1.25f) + (u >= 1.75f) +
          (u >= 2.5f) + (u >= 3.5f) + (u >= 5.0f);
  return (unsigned)(c | (x < 0.f ? 8 : 0));
}

static __device__ __forceinline__ unsigned int pack8_fp4(
    const float4& v0, const float4& v1, float s) {
  return enc4(v0.x * s)        | (enc4(v0.y * s) << 4)  |
         (enc4(v0.z * s) << 8) | (enc4(v0.w * s) << 12) |
         (enc4(v1.x * s) << 16)| (enc4(v1.y * s) << 20) |
         (enc4(v1.z * s) << 24)| (enc4(v1.w * s) << 28);
}

// ---------------------------------------------------------------------------
// Kernel 1: per-row L2 normalize.
// mat 0 (source):    fp8 row-major a8row (colsum) + fp4 row-major a4 (gemm)
// mat 1 (bc_target): fp8 row-major b8 (colsum); rows 0..16 zero zbuf
// mat 2 (raw_target): fp4 row-major c4 (gemm)
// fp4 rows are 1024B: dword t covers elements [8t,8t+8), nibble i = elt 8t+i.
// grid (NR, 3), block 256.
// ---------------------------------------------------------------------------
__global__ __launch_bounds__(256) void normalize_kernel(
    const float* __restrict__ src, const float* __restrict__ bc,
    const float* __restrict__ raw,
    unsigned char* __restrict__ a8row, unsigned int* __restrict__ a4,
    unsigned char* __restrict__ b8, unsigned int* __restrict__ c4,
    float* __restrict__ zbuf) {
  const int row = blockIdx.x;
  const int mat = blockIdx.y;
  const int tid = threadIdx.x;
  const float* base = (mat == 0) ? src : ((mat == 1) ? bc : raw);
  const float4* b4 = (const float4*)(base + (size_t)row * DD);

  if (mat == 1 && row < 17) {
    const int idx = row * 256 + tid;
    if (idx < 2 * DD + 1) zbuf[idx] = 0.f;
  }

  float4 v0 = b4[tid * 2];
  float4 v1 = b4[tid * 2 + 1];
  float ss = v0.x * v0.x + v0.y * v0.y + v0.z * v0.z + v0.w * v0.w +
             v1.x * v1.x + v1.y * v1.y + v1.z * v1.z + v1.w * v1.w;
  #pragma unroll
  for (int off = 32; off > 0; off >>= 1) ss += __shfl_down(ss, off, 64);

  __shared__ float sred[4];
  __shared__ float sinv;
  if ((tid & 63) == 0) sred[tid >> 6] = ss;
  __syncthreads();
  if (tid == 0) sinv = rsqrtf(sred[0] + sred[1] + sred[2] + sred[3]);
  __syncthreads();

  if (mat == 2) {  // raw_target -> fp4 only
    c4[row * (DD / 8) + tid] = pack8_fp4(v0, v1, sinv * QS4);
    return;
  }

  // fp8 pack (HW cvt, RNE, OCP e4m3 on gfx950)
  const float s = sinv * QSCALE;
  int d0 = __builtin_amdgcn_cvt_pk_fp8_f32(v0.x * s, v0.y * s, 0, false);
  d0 = __builtin_amdgcn_cvt_pk_fp8_f32(v0.z * s, v0.w * s, d0, true);
  int d1 = __builtin_amdgcn_cvt_pk_fp8_f32(v1.x * s, v1.y * s, 0, false);
  d1 = __builtin_amdgcn_cvt_pk_fp8_f32(v1.z * s, v1.w * s, d1, true);
  int2 o; o.x = d0; o.y = d1;
  if (mat == 0) {
    *(int2*)(a8row + (size_t)row * DD + tid * 8) = o;
    a4[row * (DD / 8) + tid] = pack8_fp4(v0, v1, sinv * QS4);
  } else {
    *(int2*)(b8 + (size_t)row * DD + tid * 8) = o;
  }
}

// ---------------------------------------------------------------------------
// Kernel 2: MX-fp4 MFMA GEMM a_n @ c_n^T with fused sum(exp(sim/T)) epilogue.
// Round-9: SINGLE-buffer fp4 (32KB LDS) + __launch_bounds__(256,3) -> 3
// blocks/CU (r8 dbuf = 64KB = 2 blocks/CU; r4 showed single-buf == dbuf, so
// spend the LDS on occupancy instead — inter-block overlap covers each
// block's barrier drain, m114). Plus XCD-aware swizzle: flat%8 -> 8
// rectangles of 8br x 16bc, per-XCD working set A 1MB + B 2MB = 3MB < 4MB
// L2 (the r6/r7 fp8 plateau was L3-refetch: 8MB A > 4MB L2 thrashed).
// Frags loaded per-k-step (halves register liveness vs r8).
// fp4 e2m1 operands (cbsz=blgp=4, identity E8M0 scales); A/B use identical
// per-lane nibble packing so the HW k-order cancels (absmax 0.0 in r8).
// grid (32, 32) remapped, block 256 (4 waves; 64x64 quadrant each).
// ---------------------------------------------------------------------------
__global__ __launch_bounds__(256, 3) void gemm_expsum_kernel(
    const unsigned char* __restrict__ a4, const unsigned char* __restrict__ c4,
    float* __restrict__ S_part) {
  __shared__ unsigned char As[128 * 128];  // [row][chunk^(row&7)] 16KB
  __shared__ unsigned char Cs[128 * 128];
  const int tid = threadIdx.x;
  const int lane = tid & 63;
  const int wave = tid >> 6;
  const int wr = wave >> 1;       // wave row quadrant (0/1)
  const int wc = wave & 1;        // wave col quadrant (0/1)
  const int quad = lane >> 4;     // k-sub-block selector within a k-step
  const int l16 = lane & 15;

  // XCD-aware swizzle (assumes HW round-robins flat id over 8 XCDs; any
  // other assignment is just a permutation — locality only, never wrong).
  const int flat = blockIdx.y * 32 + blockIdx.x;
  const int xcd = flat & 7, slot = flat >> 3;
  const int br = (xcd >> 1) * 8 + ((slot >> 3) & 7);
  const int bc = (xcd & 1) * 16 + (slot >> 6) * 8 + (slot & 7);

  floatx4 acc[4][4] = {};

  // staging: per matrix, 16 windows of 1KB (8 rows x 128B); 4/wave.
  // fp4 row = 1024B; ktile kt covers row bytes [kt*128, kt*128+128).
  const int wrow = lane >> 3;
  const int csrc = (lane & 7) ^ (wrow & 7);
  const unsigned char* gA[4];
  const unsigned char* gC[4];
  int ldsOff[4];
  #pragma unroll
  for (int q = 0; q < 4; q++) {
    const int m = wave * 4 + q;
    const int row = m * 8 + wrow;
    gA[q] = a4 + (size_t)(br * 128 + row) * 1024 + csrc * 16;
    gC[q] = c4 + (size_t)(bc * 128 + row) * 1024 + csrc * 16;
    ldsOff[q] = m * 1024;
  }

  const int NKT = DD / 256;  // 8 ktiles of K=256 elements (128B/row)
  for (int kt = 0; kt < NKT; kt++) {
    #pragma unroll
    for (int q = 0; q < 4; q++) {
      async_copy16(gA[q], &As[ldsOff[q]]);
      async_copy16(gC[q], &Cs[ldsOff[q]]);
      gA[q] += 128; gC[q] += 128;
    }
    __syncthreads();  // drains vmcnt (staging) + barrier

    // k-step s: lane(quad,l16) holds 32 nibbles = 16B at logical chunk
    // s*4+quad (physical ^(r&7)); fp4 uses v[0:3] of the A/B field.
    #pragma unroll
    for (int s = 0; s < 2; s++) {
      int4v af[4], bf[4];
      #pragma unroll
      for (int i = 0; i < 4; i++) {
        const int r = wr * 64 + i * 16 + l16;
        const int pc = (s * 4 + quad) ^ (r & 7);
        af[i] = *(const int4v*)&As[r * 128 + pc * 16];
      }
      #pragma unroll
      for (int j = 0; j < 4; j++) {
        const int r = wc * 64 + j * 16 + l16;
        const int pc = (s * 4 + quad) ^ (r & 7);
        bf[j] = *(const int4v*)&Cs[r * 128 + pc * 16];
      }
      #pragma unroll
      for (int i = 0; i < 4; i++) {
        const int8v a8v = int8v{af[i][0], af[i][1], af[i][2], af[i][3],
                                0, 0, 0, 0};
        #pragma unroll
        for (int j = 0; j < 4; j++) {
          const int8v b8v = int8v{bf[j][0], bf[j][1], bf[j][2], bf[j][3],
                                  0, 0, 0, 0};
          acc[i][j] = __builtin_amdgcn_mfma_scale_f32_16x16x128_f8f6f4(
              a8v, b8v, acc[i][j], 4 /*cbsz: fp4*/, 4 /*blgp: fp4*/,
              0, 0x7F7F7F7F, 0, 0x7F7F7F7F /*E8M0 identity scales*/);
        }
      }
    }
    __syncthreads();  // all waves done reading LDS before restage
  }

  // epilogue: sum exp(sim/T) over this block's 128x128 tile; acc = 4096*sim.
  float local = 0.f;
  #pragma unroll
  for (int i = 0; i < 4; i++)
    #pragma unroll
    for (int j = 0; j < 4; j++)
      #pragma unroll
      for (int r = 0; r < 4; r++)
        local += __expf(acc[i][j][r] * ACC4_TO_LOGIT);
  #pragma unroll
  for (int off = 32; off > 0; off >>= 1) local += __shfl_down(local, off, 64);
  __shared__ float red[4];
  if (lane == 0) red[wave] = local;
  __syncthreads();
  if (tid == 0) S_part[br * 32 + bc] = red[0] + red[1] + red[2] + red[3];
}

// ---------------------------------------------------------------------------
// Kernel 3: column sums of a8row/b8 (fp8) + fused finalize (two-level
// reduction; last-block-done finalize). Round-9: 256 blocks (1/CU — the
// 128-block version left half the chip idle). Block b: cols
// [(b&7)*256 + ...], rows [(b>>3)*128, +128) in 4 strided passes.
// ---------------------------------------------------------------------------
__global__ __launch_bounds__(256) void colsum_finalize_kernel(
    const unsigned char* __restrict__ a8, const unsigned char* __restrict__ b8,
    float* __restrict__ s_a, float* __restrict__ s_b,
    float* __restrict__ counter, const float* __restrict__ S_part,
    float* __restrict__ out) {
  __shared__ float lds[32 * 264];
  const int tid = threadIdx.x;
  const int rt = tid >> 3;          // 0..31: row-thread
  const int ct = tid & 7;           // 0..7 : col-thread (32 cols each)
  const int cg = blockIdx.x & 7;    // col group (256 cols)
  const int rg = blockIdx.x >> 3;   // row group (128 rows)
  const int cbase = cg * 256 + ct * 32;
  const int rbase = rg * 128 + rt;

  float accA[32], accB[32];
  #pragma unroll
  for (int i = 0; i < 32; i++) { accA[i] = 0.f; accB[i] = 0.f; }

  #pragma unroll
  for (int k = 0; k < 4; k++) {
    const size_t off = (size_t)(rbase + k * 32) * DD + cbase;
    const int8v ra = *(const int8v*)(a8 + off);  // 32B coalesced
    const int8v rb = *(const int8v*)(b8 + off);
    #pragma unroll
    for (int u = 0; u < 8; u++) {
      floatx2 lo = __builtin_amdgcn_cvt_pk_f32_fp8(ra[u], false);
      floatx2 hi = __builtin_amdgcn_cvt_pk_f32_fp8(ra[u], true);
      accA[u * 4 + 0] += lo[0]; accA[u * 4 + 1] += lo[1];
      accA[u * 4 + 2] += hi[0]; accA[u * 4 + 3] += hi[1];
      lo = __builtin_amdgcn_cvt_pk_f32_fp8(rb[u], false);
      hi = __builtin_amdgcn_cvt_pk_f32_fp8(rb[u], true);
      accB[u * 4 + 0] += lo[0]; accB[u * 4 + 1] += lo[1];
      accB[u * 4 + 2] += hi[0]; accB[u * 4 + 3] += hi[1];
    }
  }

  // phase A: transpose-reduce accA across the 32 row-threads
  #pragma unroll
  for (int i = 0; i < 32; i += 4)
    *(floatx4*)&lds[rt * 264 + ct * 32 + i] =
        floatx4{accA[i], accA[i + 1], accA[i + 2], accA[i + 3]};
  __syncthreads();
  float sA = 0.f;
  #pragma unroll 8
  for (int r = 0; r < 32; r++) sA += lds[r * 264 + tid];
  atomicAdd(&s_a[cg * 256 + tid], sA);
  __syncthreads();  // all reads of lds done before phase B overwrites

  // phase B
  #pragma unroll
  for (int i = 0; i < 32; i += 4)
    *(floatx4*)&lds[rt * 264 + ct * 32 + i] =
        floatx4{accB[i], accB[i + 1], accB[i + 2], accB[i + 3]};
  __syncthreads();
  float sB = 0.f;
  #pragma unroll 8
  for (int r = 0; r < 32; r++) sB += lds[r * 264 + tid];
  atomicAdd(&s_b[cg * 256 + tid], sB);

  __threadfence();   // order our atomics before the counter bump
  __syncthreads();
  __shared__ bool amLast;
  if (tid == 0) amLast = (atomicAdd(counter, 1.0f) == 255.0f);
  __syncthreads();
  if (!amLast) return;
  __threadfence();   // acquire side

  float dot = 0.f;
  for (int d = tid; d < DD; d += 256)
    dot += atomicAdd(&s_a[d], 0.f) * atomicAdd(&s_b[d], 0.f);  // coherent reads
  float se = 0.f;
  for (int i = tid; i < 1024; i += 256) se += S_part[i];  // gemm ended: plain ok

  #pragma unroll
  for (int off = 32; off > 0; off >>= 1) {
    dot += __shfl_down(dot, off, 64);
    se += __shfl_down(se, off, 64);
  }
  __shared__ float redd[4], reds[4];
  if ((tid & 63) == 0) { redd[tid >> 6] = dot; reds[tid >> 6] = se; }
  __syncthreads();
  if (tid == 0) {
    const float dt = redd[0] + redd[1] + redd[2] + redd[3];
    const float st = reds[0] + reds[1] + reds[2] + reds[3];
    out[0] = logf(st) - dt * (ACC_TO_LOGIT / ((float)NR * (float)NR));
  }
}

extern "C" void kernel_launch(void* const* d_in, const int* in_sizes, int n_in,
                              void* d_out, int out_size, void* d_ws, size_t ws_size,
                              hipStream_t stream) {
  const float* src = (const float*)d_in[0];
  const float* bc  = (const float*)d_in[1];
  const float* raw = (const float*)d_in[2];

  char* ws = (char*)d_ws;
  unsigned char* a8row = (unsigned char*)ws;                             // 8 MiB
  unsigned char* b8 = (unsigned char*)(ws + (size_t)8 * 1024 * 1024);    // 8 MiB
  unsigned int* a4  = (unsigned int*)(ws + (size_t)16 * 1024 * 1024);    // 4 MiB
  unsigned int* c4  = (unsigned int*)(ws + (size_t)20 * 1024 * 1024);    // 4 MiB
  float* zbuf  = (float*)(ws + (size_t)24 * 1024 * 1024);  // s_a|s_b|counter
  float* s_a   = zbuf;
  float* s_b   = zbuf + DD;
  float* counter = zbuf + 2 * DD;
  float* S_part = (float*)(ws + (size_t)24 * 1024 * 1024 + 20480);  // 4 KiB

  normalize_kernel<<<dim3(NR, 3), 256, 0, stream>>>(src, bc, raw, a8row, a4,
                                                    b8, c4, zbuf);
  gemm_expsum_kernel<<<dim3(32, 32), 256, 0, stream>>>(
      (const unsigned char*)a4, (const unsigned char*)c4, S_part);
  colsum_finalize_kernel<<<256, 256, 0, stream>>>(a8row, b8, s_a, s_b, counter,
                                                  S_part, (float*)d_out);
}

// Round 10
// 165.292 us; speedup vs baseline: 1.0329x; 1.0329x over previous
//
#include <hip/hip_runtime.h>
#include <hip/hip_bf16.h>

// Problem constants (N=4096 rows, D=2048 cols, T=0.5 -> 1/T = 2)
#define NR 4096
#define DD 2048
#define INV_T 2.0f
// fp8 path (colsum): a_n*32 in e4m3 range; dot accumulates 1024*sim
#define QSCALE 32.0f
#define ACC_TO_LOGIT (INV_T / (QSCALE * QSCALE))  // 2/1024, colsum dot
// fp4 path (gemm): a_n*64 ~ N(0,1.41) into e2m1 range ±6 (±4.2 sigma);
// MFMA acc = 4096*sim
#define QS4 64.0f
#define ACC4_TO_LOGIT (INV_T / (QS4 * QS4))  // 2/4096, gemm logits

typedef __attribute__((ext_vector_type(2))) float floatx2;
typedef __attribute__((ext_vector_type(4))) float floatx4;
typedef __attribute__((ext_vector_type(4))) int int4v;
typedef __attribute__((ext_vector_type(8))) int int8v;

static __device__ __forceinline__ void async_copy16(const void* g, void* lds) {
  __builtin_amdgcn_global_load_lds((const __attribute__((address_space(1))) void*)g,
                                   (__attribute__((address_space(3))) void*)lds,
                                   16, 0, 0);
}

// e2m1 encode of pre-scaled x: values {0,.5,1,1.5,2,3,4,6}, clamp at 6,
// round-to-nearest via midpoint thresholds. Returns 4-bit code.
static __device__ __forceinline__ unsigned int enc4(float x) {
  float u = fminf(fabsf(x), 6.0f);
  int c = (u >= 0.25f) + (u >= 0.75f) + (u >= 1.25f) + (u >= 1.75f) +
          (u >= 2.5f) + (u >= 3.5f) + (u >= 5.0f);
  return (unsigned)(c | (x < 0.f ? 8 : 0));
}

static __device__ __forceinline__ unsigned int pack8_fp4(
    const float4& v0, const float4& v1, float s) {
  return enc4(v0.x * s)        | (enc4(v0.y * s) << 4)  |
         (enc4(v0.z * s) << 8) | (enc4(v0.w * s) << 12) |
         (enc4(v1.x * s) << 16)| (enc4(v1.y * s) << 20) |
         (enc4(v1.z * s) << 24)| (enc4(v1.w * s) << 28);
}

// ---------------------------------------------------------------------------
// Kernel 1: per-row L2 normalize.  (r8 configuration — session best)
// mat 0 (source):    fp8 row-major a8row (colsum) + fp4 row-major a4 (gemm)
// mat 1 (bc_target): fp8 row-major b8 (colsum); rows 0..16 zero zbuf
// mat 2 (raw_target): fp4 row-major c4 (gemm)
// fp4 rows are 1024B: dword t covers elements [8t,8t+8), nibble i = elt 8t+i.
// grid (NR, 3), block 256.
// ---------------------------------------------------------------------------
__global__ __launch_bounds__(256) void normalize_kernel(
    const float* __restrict__ src, const float* __restrict__ bc,
    const float* __restrict__ raw,
    unsigned char* __restrict__ a8row, unsigned int* __restrict__ a4,
    unsigned char* __restrict__ b8, unsigned int* __restrict__ c4,
    float* __restrict__ zbuf) {
  const int row = blockIdx.x;
  const int mat = blockIdx.y;
  const int tid = threadIdx.x;
  const float* base = (mat == 0) ? src : ((mat == 1) ? bc : raw);
  const float4* b4 = (const float4*)(base + (size_t)row * DD);

  if (mat == 1 && row < 17) {
    const int idx = row * 256 + tid;
    if (idx < 2 * DD + 1) zbuf[idx] = 0.f;
  }

  float4 v0 = b4[tid * 2];
  float4 v1 = b4[tid * 2 + 1];
  float ss = v0.x * v0.x + v0.y * v0.y + v0.z * v0.z + v0.w * v0.w +
             v1.x * v1.x + v1.y * v1.y + v1.z * v1.z + v1.w * v1.w;
  #pragma unroll
  for (int off = 32; off > 0; off >>= 1) ss += __shfl_down(ss, off, 64);

  __shared__ float sred[4];
  __shared__ float sinv;
  if ((tid & 63) == 0) sred[tid >> 6] = ss;
  __syncthreads();
  if (tid == 0) sinv = rsqrtf(sred[0] + sred[1] + sred[2] + sred[3]);
  __syncthreads();

  if (mat == 2) {  // raw_target -> fp4 only
    c4[row * (DD / 8) + tid] = pack8_fp4(v0, v1, sinv * QS4);
    return;
  }

  // fp8 pack (HW cvt, RNE, OCP e4m3 on gfx950)
  const float s = sinv * QSCALE;
  int d0 = __builtin_amdgcn_cvt_pk_fp8_f32(v0.x * s, v0.y * s, 0, false);
  d0 = __builtin_amdgcn_cvt_pk_fp8_f32(v0.z * s, v0.w * s, d0, true);
  int d1 = __builtin_amdgcn_cvt_pk_fp8_f32(v1.x * s, v1.y * s, 0, false);
  d1 = __builtin_amdgcn_cvt_pk_fp8_f32(v1.z * s, v1.w * s, d1, true);
  int2 o; o.x = d0; o.y = d1;
  if (mat == 0) {
    *(int2*)(a8row + (size_t)row * DD + tid * 8) = o;
    a4[row * (DD / 8) + tid] = pack8_fp4(v0, v1, sinv * QS4);
  } else {
    *(int2*)(b8 + (size_t)row * DD + tid * 8) = o;
  }
}

// ---------------------------------------------------------------------------
// Kernel 2: MX-fp4 MFMA GEMM a_n @ c_n^T with fused sum(exp(sim/T)) epilogue.
// r8 configuration (session best): fp4 e2m1 operands (cbsz=blgp=4, identity
// E8M0 scales), LDS tile 128 rows x 128B (K=256), dbuf both operands, XOR
// source-swizzle, 2 MFMA k-steps/tile. fp4 halves bytes/FLOP vs fp8 — the
// r4/r6/r7 fp8 plateau (41-42us across three K-loop structures) was
// L2-service traffic-bound; fp4 cut it to ~27us. r9's occupancy-3 +
// single-buf + XCD-swizzle variant regressed — reverted.
// grid (32 bc, 32 br), block 256 (4 waves; each wave owns a 64x64 quadrant).
// ---------------------------------------------------------------------------
__global__ __launch_bounds__(256, 2) void gemm_expsum_kernel(
    const unsigned char* __restrict__ a4, const unsigned char* __restrict__ c4,
    float* __restrict__ S_part) {
  __shared__ unsigned char As[2][128 * 128];  // [buf][row][chunk^(row&7)]
  __shared__ unsigned char Cs[2][128 * 128];
  const int tid = threadIdx.x;
  const int lane = tid & 63;
  const int wave = tid >> 6;
  const int wr = wave >> 1;       // wave row quadrant (0/1)
  const int wc = wave & 1;        // wave col quadrant (0/1)
  const int quad = lane >> 4;     // k-sub-block selector within a k-step
  const int l16 = lane & 15;
  const int bc = blockIdx.x, br = blockIdx.y;

  floatx4 acc[4][4] = {};

  // staging: per matrix+buffer, 16 windows of 1KB (8 rows x 128B); 4/wave.
  // fp4 row = 1024B; ktile kt covers row bytes [kt*128, kt*128+128).
  const int wrow = lane >> 3;
  const int csrc = (lane & 7) ^ (wrow & 7);
  const unsigned char* gA[4];
  const unsigned char* gC[4];
  int ldsOff[4];
  #pragma unroll
  for (int q = 0; q < 4; q++) {
    const int m = wave * 4 + q;
    const int row = m * 8 + wrow;
    gA[q] = a4 + (size_t)(br * 128 + row) * 1024 + csrc * 16;
    gC[q] = c4 + (size_t)(bc * 128 + row) * 1024 + csrc * 16;
    ldsOff[q] = m * 1024;
  }

  // prologue: stage ktile 0 into buffer 0
  #pragma unroll
  for (int q = 0; q < 4; q++) {
    async_copy16(gA[q], &As[0][ldsOff[q]]);
    async_copy16(gC[q], &Cs[0][ldsOff[q]]);
    gA[q] += 128; gC[q] += 128;
  }

  const int NKT = DD / 256;  // 8 ktiles
  #pragma unroll 2
  for (int kt = 0; kt < NKT; kt++) {
    const int cur = kt & 1;
    __syncthreads();  // drains vmcnt: ktile-kt stage (issued one body ago)

    if (kt < NKT - 1) {  // prefetch kt+1 into the other buffer
      #pragma unroll
      for (int q = 0; q < 4; q++) {
        async_copy16(gA[q], &As[cur ^ 1][ldsOff[q]]);
        async_copy16(gC[q], &Cs[cur ^ 1][ldsOff[q]]);
        gA[q] += 128; gC[q] += 128;
      }
    }

    // fragments: k-step s, lane(quad,l16): 32 nibbles = 16B at logical
    // chunk s*4+quad (physical ^(r&7)). fp4 uses v[0:3] of the A/B field.
    int4v af[2][4], bf[2][4];
    #pragma unroll
    for (int s = 0; s < 2; s++) {
      #pragma unroll
      for (int i = 0; i < 4; i++) {
        const int r = wr * 64 + i * 16 + l16;
        const int pc = (s * 4 + quad) ^ (r & 7);
        af[s][i] = *(const int4v*)&As[cur][r * 128 + pc * 16];
      }
      #pragma unroll
      for (int j = 0; j < 4; j++) {
        const int r = wc * 64 + j * 16 + l16;
        const int pc = (s * 4 + quad) ^ (r & 7);
        bf[s][j] = *(const int4v*)&Cs[cur][r * 128 + pc * 16];
      }
    }
    #pragma unroll
    for (int s = 0; s < 2; s++)
      #pragma unroll
      for (int i = 0; i < 4; i++) {
        const int8v a8v = int8v{af[s][i][0], af[s][i][1], af[s][i][2],
                                af[s][i][3], 0, 0, 0, 0};
        #pragma unroll
        for (int j = 0; j < 4; j++) {
          const int8v b8v = int8v{bf[s][j][0], bf[s][j][1], bf[s][j][2],
                                  bf[s][j][3], 0, 0, 0, 0};
          acc[i][j] = __builtin_amdgcn_mfma_scale_f32_16x16x128_f8f6f4(
              a8v, b8v, acc[i][j], 4 /*cbsz: fp4*/, 4 /*blgp: fp4*/,
              0, 0x7F7F7F7F, 0, 0x7F7F7F7F /*E8M0 identity scales*/);
        }
      }
  }

  // epilogue: sum exp(sim/T) over this block's 128x128 tile; acc = 4096*sim.
  float local = 0.f;
  #pragma unroll
  for (int i = 0; i < 4; i++)
    #pragma unroll
    for (int j = 0; j < 4; j++)
      #pragma unroll
      for (int r = 0; r < 4; r++)
        local += __expf(acc[i][j][r] * ACC4_TO_LOGIT);
  #pragma unroll
  for (int off = 32; off > 0; off >>= 1) local += __shfl_down(local, off, 64);
  __shared__ float red[4];
  if (lane == 0) red[wave] = local;
  __syncthreads();
  if (tid == 0) S_part[br * 32 + bc] = red[0] + red[1] + red[2] + red[3];
}

// ---------------------------------------------------------------------------
// Kernel 3: column sums of a8row/b8 (fp8) + fused finalize (two-level
// reduction, 64K total atomics; last-block-done finalize). r8 configuration.
// grid 128 blocks (8 col-groups x 16 row-groups), block 256.
// ---------------------------------------------------------------------------
__global__ __launch_bounds__(256) void colsum_finalize_kernel(
    const unsigned char* __restrict__ a8, const unsigned char* __restrict__ b8,
    float* __restrict__ s_a, float* __restrict__ s_b,
    float* __restrict__ counter, const float* __restrict__ S_part,
    float* __restrict__ out) {
  __shared__ float lds[32 * 264];
  const int tid = threadIdx.x;
  const int rt = tid >> 3;          // 0..31: row-thread
  const int ct = tid & 7;           // 0..7 : col-thread (32 cols each)
  const int cg = blockIdx.x & 7;    // col group (256 cols)
  const int rg = blockIdx.x >> 3;   // row group (256 rows)
  const int cbase = cg * 256 + ct * 32;
  const int rbase = rg * 256 + rt;

  float accA[32], accB[32];
  #pragma unroll
  for (int i = 0; i < 32; i++) { accA[i] = 0.f; accB[i] = 0.f; }

  #pragma unroll
  for (int k = 0; k < 8; k++) {
    const size_t off = (size_t)(rbase + k * 32) * DD + cbase;
    const int8v ra = *(const int8v*)(a8 + off);  // 32B coalesced
    const int8v rb = *(const int8v*)(b8 + off);
    #pragma unroll
    for (int u = 0; u < 8; u++) {
      floatx2 lo = __builtin_amdgcn_cvt_pk_f32_fp8(ra[u], false);
      floatx2 hi = __builtin_amdgcn_cvt_pk_f32_fp8(ra[u], true);
      accA[u * 4 + 0] += lo[0]; accA[u * 4 + 1] += lo[1];
      accA[u * 4 + 2] += hi[0]; accA[u * 4 + 3] += hi[1];
      lo = __builtin_amdgcn_cvt_pk_f32_fp8(rb[u], false);
      hi = __builtin_amdgcn_cvt_pk_f32_fp8(rb[u], true);
      accB[u * 4 + 0] += lo[0]; accB[u * 4 + 1] += lo[1];
      accB[u * 4 + 2] += hi[0]; accB[u * 4 + 3] += hi[1];
    }
  }

  // phase A: transpose-reduce accA across the 32 row-threads
  #pragma unroll
  for (int i = 0; i < 32; i += 4)
    *(floatx4*)&lds[rt * 264 + ct * 32 + i] =
        floatx4{accA[i], accA[i + 1], accA[i + 2], accA[i + 3]};
  __syncthreads();
  float sA = 0.f;
  #pragma unroll 8
  for (int r = 0; r < 32; r++) sA += lds[r * 264 + tid];
  atomicAdd(&s_a[cg * 256 + tid], sA);
  __syncthreads();  // all reads of lds done before phase B overwrites

  // phase B
  #pragma unroll
  for (int i = 0; i < 32; i += 4)
    *(floatx4*)&lds[rt * 264 + ct * 32 + i] =
        floatx4{accB[i], accB[i + 1], accB[i + 2], accB[i + 3]};
  __syncthreads();
  float sB = 0.f;
  #pragma unroll 8
  for (int r = 0; r < 32; r++) sB += lds[r * 264 + tid];
  atomicAdd(&s_b[cg * 256 + tid], sB);

  __threadfence();   // order our atomics before the counter bump
  __syncthreads();
  __shared__ bool amLast;
  if (tid == 0) amLast = (atomicAdd(counter, 1.0f) == 127.0f);
  __syncthreads();
  if (!amLast) return;
  __threadfence();   // acquire side

  float dot = 0.f;
  for (int d = tid; d < DD; d += 256)
    dot += atomicAdd(&s_a[d], 0.f) * atomicAdd(&s_b[d], 0.f);  // coherent reads
  float se = 0.f;
  for (int i = tid; i < 1024; i += 256) se += S_part[i];  // gemm ended: plain ok

  #pragma unroll
  for (int off = 32; off > 0; off >>= 1) {
    dot += __shfl_down(dot, off, 64);
    se += __shfl_down(se, off, 64);
  }
  __shared__ float redd[4], reds[4];
  if ((tid & 63) == 0) { redd[tid >> 6] = dot; reds[tid >> 6] = se; }
  __syncthreads();
  if (tid == 0) {
    const float dt = redd[0] + redd[1] + redd[2] + redd[3];
    const float st = reds[0] + reds[1] + reds[2] + reds[3];
    out[0] = logf(st) - dt * (ACC_TO_LOGIT / ((float)NR * (float)NR));
  }
}

extern "C" void kernel_launch(void* const* d_in, const int* in_sizes, int n_in,
                              void* d_out, int out_size, void* d_ws, size_t ws_size,
                              hipStream_t stream) {
  const float* src = (const float*)d_in[0];
  const float* bc  = (const float*)d_in[1];
  const float* raw = (const float*)d_in[2];

  char* ws = (char*)d_ws;
  unsigned char* a8row = (unsigned char*)ws;                             // 8 MiB
  unsigned char* b8 = (unsigned char*)(ws + (size_t)8 * 1024 * 1024);    // 8 MiB
  unsigned int* a4  = (unsigned int*)(ws + (size_t)16 * 1024 * 1024);    // 4 MiB
  unsigned int* c4  = (unsigned int*)(ws + (size_t)20 * 1024 * 1024);    // 4 MiB
  float* zbuf  = (float*)(ws + (size_t)24 * 1024 * 1024);  // s_a|s_b|counter
  float* s_a   = zbuf;
  float* s_b   = zbuf + DD;
  float* counter = zbuf + 2 * DD;
  float* S_part = (float*)(ws + (size_t)24 * 1024 * 1024 + 20480);  // 4 KiB

  normalize_kernel<<<dim3(NR, 3), 256, 0, stream>>>(src, bc, raw, a8row, a4,
                                                    b8, c4, zbuf);
  gemm_expsum_kernel<<<dim3(32, 32), 256, 0, stream>>>(
      (const unsigned char*)a4, (const unsigned char*)c4, S_part);
  colsum_finalize_kernel<<<128, 256, 0, stream>>>(a8row, b8, s_a, s_b, counter,
                                                  S_part, (float*)d_out);
}